// Round 24
// baseline (258.945 us; speedup 1.0000x reference)
//
#include <hip/hip_runtime.h>
#include <hip/hip_bf16.h>

typedef __bf16 bf16x8 __attribute__((ext_vector_type(8)));
typedef __bf16 bf16x4 __attribute__((ext_vector_type(4)));
typedef float  f32x4  __attribute__((ext_vector_type(4)));

#define MFMA16(a, b, c) __builtin_amdgcn_mfma_f32_16x16x32_bf16((a), (b), (c), 0, 0, 0)

__device__ __forceinline__ void gload16(const void* g, void* l) {
  __builtin_amdgcn_global_load_lds(
      (const __attribute__((address_space(1))) unsigned int*)g,
      (__attribute__((address_space(3))) unsigned int*)l, 16, 0, 0);
}

// ---------------------------------------------------------------- f32 -> bf16 pack, all 6 weights in one launch
__global__ __launch_bounds__(256) void cvt6_kernel(
    const float* __restrict__ wq, const float* __restrict__ wk,
    const float* __restrict__ wv, const float* __restrict__ wo,
    const float* __restrict__ w1, const float* __restrict__ w2,
    __bf16* __restrict__ dst) {
  const long i = ((long)blockIdx.x * 256 + threadIdx.x) * 8;  // [0, 12M)
  const long M1 = 1048576;
  const float* src;
  long off;
  if      (i < 1 * M1) { src = wq; off = i; }
  else if (i < 2 * M1) { src = wk; off = i - 1 * M1; }
  else if (i < 3 * M1) { src = wv; off = i - 2 * M1; }
  else if (i < 4 * M1) { src = wo; off = i - 3 * M1; }
  else if (i < 8 * M1) { src = w1; off = i - 4 * M1; }
  else                 { src = w2; off = i - 8 * M1; }
  float4 a = *(const float4*)&src[off];
  float4 b = *(const float4*)&src[off + 4];
  bf16x8 o;
  o[0] = (__bf16)a.x; o[1] = (__bf16)a.y; o[2] = (__bf16)a.z; o[3] = (__bf16)a.w;
  o[4] = (__bf16)b.x; o[5] = (__bf16)b.y; o[6] = (__bf16)b.z; o[7] = (__bf16)b.w;
  *(bf16x8*)&dst[i] = o;
}

// pack 3 bias vectors (1024 each) into one f32[3072]
__global__ __launch_bounds__(256) void pack3_kernel(
    const float* __restrict__ a, const float* __restrict__ b,
    const float* __restrict__ c, float* __restrict__ o) {
  const int i = blockIdx.x * 256 + threadIdx.x;
  o[i] = i < 1024 ? a[i] : (i < 2048 ? b[i - 1024] : c[i - 2048]);
}

// ---------------------------------------------------------------- LayerNorm (f32 in -> bf16 out)
__global__ __launch_bounds__(256) void ln_kernel(
    const float* __restrict__ in, const float* __restrict__ gg,
    const float* __restrict__ bb, __bf16* __restrict__ out) {
  __shared__ float sred[8];
  const long row = blockIdx.x;
  const int tid = threadIdx.x;
  float4 u = *(const float4*)&in[row * 1024 + tid * 4];
  float f[4] = {u.x, u.y, u.z, u.w};
  float s = 0.f, sq = 0.f;
#pragma unroll
  for (int j = 0; j < 4; ++j) { s += f[j]; sq += f[j] * f[j]; }
#pragma unroll
  for (int d = 32; d; d >>= 1) { s += __shfl_xor(s, d); sq += __shfl_xor(sq, d); }
  const int w = tid >> 6;
  if ((tid & 63) == 0) { sred[w * 2] = s; sred[w * 2 + 1] = sq; }
  __syncthreads();
  s  = sred[0] + sred[2] + sred[4] + sred[6];
  sq = sred[1] + sred[3] + sred[5] + sred[7];
  const float mean = s * (1.f / 1024.f);
  const float var  = sq * (1.f / 1024.f) - mean * mean;
  const float rstd = rsqrtf(var + 1e-5f);
  float4 gv = *(const float4*)&gg[tid * 4];
  float4 bv = *(const float4*)&bb[tid * 4];
  bf16x4 ov;
  ov[0] = (__bf16)((f[0] - mean) * rstd * gv.x + bv.x);
  ov[1] = (__bf16)((f[1] - mean) * rstd * gv.y + bv.y);
  ov[2] = (__bf16)((f[2] - mean) * rstd * gv.z + bv.z);
  ov[3] = (__bf16)((f[3] - mean) * rstd * gv.w + bv.w);
  *(bf16x4*)&out[row * 1024 + tid * 4] = ov;
}

// ---------------------------------------------------------------- RoPE (in place on packed qkv, LD=3072), bf16x8
__global__ __launch_bounds__(256) void rope_kernel(
    __bf16* __restrict__ qkv, const float* __restrict__ freqs) {
  const int idx = blockIdx.x * 256 + threadIdx.x;   // [0, 4096*16*8)
  const int isq = (blockIdx.y == 0);
  __bf16* p = qkv + (isq ? 0 : 1024);
  const float scale = isq ? 0.125f : 1.0f;
  const int token = idx >> 7;
  const int wi = idx & 127;
  const int head = wi >> 3, i4 = wi & 7;
  const int spos = token & 2047;
  float4 fv = *(const float4*)&freqs[spos * 32 + i4 * 4];
  const long off = (long)token * 3072 + head * 64 + i4 * 8;
  bf16x8 u = *(bf16x8*)&p[off];
  float sn[4], cs[4];
  sincosf(fv.x, &sn[0], &cs[0]);
  sincosf(fv.y, &sn[1], &cs[1]);
  sincosf(fv.z, &sn[2], &cs[2]);
  sincosf(fv.w, &sn[3], &cs[3]);
  bf16x8 ov;
#pragma unroll
  for (int j = 0; j < 4; ++j) {
    const float x0 = (float)u[2 * j], x1 = (float)u[2 * j + 1];
    ov[2 * j]     = (__bf16)((x0 * cs[j] - x1 * sn[j]) * scale);
    ov[2 * j + 1] = (__bf16)((x1 * cs[j] + x0 * sn[j]) * scale);
  }
  *(bf16x8*)&p[off] = ov;
}

// ---------------------------------------------------------------- GEMM 128x64 tile, 3-buffer 2-deep pipeline
// + T2 LDS XOR-swizzle + T1 XCD swizzle. Counted vmcnt + raw barrier. (Wo-proj only now.)
enum { EPI_NONE = 0, EPI_GELU = 1, EPI_RES = 2 };

template <int EPI, typename OT, int BN>
__global__ __launch_bounds__(256) void gemm_bt(
    const __bf16* __restrict__ A, const __bf16* __restrict__ W,
    const float* __restrict__ bias, const float* __restrict__ res,
    OT* __restrict__ out, int M, int N, int K) {
  static_assert(BN == 64, "vmcnt count hardcoded for 6 loads/stage");
  constexpr int NI = BN / 32;          // fragments per wave along N
  __shared__ __bf16 lsA[3][128 * 64];
  __shared__ __bf16 lsB[3][BN * 64];
  const int tid = threadIdx.x, lane = tid & 63, w = tid >> 6;
  const int lo = lane & 15, hi = lane >> 4;
  const int gx = gridDim.x;
  int wgid = blockIdx.y * gx + blockIdx.x;
  { const int qq = (gx * gridDim.y) >> 3; wgid = (wgid & 7) * qq + (wgid >> 3); }
  const int bm = wgid / gx, bn = wgid % gx;
  const int wm = w >> 1, wn = w & 1;
  const long Kl = K, Nl = N;
  const long a_row0 = (long)bm * 128, b_row0 = (long)bn * BN;
  const int pr_row = lane >> 3;
  const int pr_scol = ((lane & 7) ^ (lane >> 3)) * 8;   // T2 inverse-swizzled source col

  auto stage = [&](int t, int buf) {   // 6 gload16 per wave (4 A + 2 B), linear LDS dest
    const int kt = t * 64;
#pragma unroll
    for (int p = 0; p < 4; ++p) {
      const int seg = p * 4 + w;
      const int row = seg * 8 + pr_row;
      gload16(A + (a_row0 + row) * Kl + kt + pr_scol, (char*)lsA[buf] + seg * 1024);
    }
#pragma unroll
    for (int p = 0; p < BN / 32; ++p) {
      const int seg = p * 4 + w;
      const int row = seg * 8 + pr_row;
      gload16(W + (b_row0 + row) * Kl + kt + pr_scol, (char*)lsB[buf] + seg * 1024);
    }
  };

  f32x4 acc[4][NI];
  const f32x4 fz = {0.f, 0.f, 0.f, 0.f};
#pragma unroll
  for (int i = 0; i < 4; ++i)
#pragma unroll
    for (int j = 0; j < NI; ++j) acc[i][j] = fz;

  const int nk = K >> 6;
  stage(0, 0);
  stage(1, 1);

  for (int n = 0; n < nk; ++n) {
    if (n + 1 < nk) asm volatile("s_waitcnt vmcnt(6)" ::: "memory");
    else            asm volatile("s_waitcnt vmcnt(0)" ::: "memory");
    __builtin_amdgcn_s_barrier();
    if (n + 2 < nk) stage(n + 2, (n + 2) % 3);
    const int cur = n % 3;
#pragma unroll
    for (int kk = 0; kk < 2; ++kk) {
      bf16x8 af[4], bfr[NI];
#pragma unroll
      for (int i = 0; i < 4; ++i) {
        const int row = wm * 64 + i * 16 + lo;
        af[i] = *(const bf16x8*)((char*)lsA[cur] + row * 128 +
                                 ((kk * 64 + 16 * hi) ^ ((row & 7) << 4)));
      }
#pragma unroll
      for (int i = 0; i < NI; ++i) {
        const int row = wn * (BN / 2) + i * 16 + lo;
        bfr[i] = *(const bf16x8*)((char*)lsB[cur] + row * 128 +
                                  ((kk * 64 + 16 * hi) ^ ((row & 7) << 4)));
      }
#pragma unroll
      for (int mi = 0; mi < 4; ++mi)
#pragma unroll
        for (int ni = 0; ni < NI; ++ni)
          acc[mi][ni] = MFMA16(af[mi], bfr[ni], acc[mi][ni]);
    }
  }

#pragma unroll
  for (int mi = 0; mi < 4; ++mi) {
#pragma unroll
    for (int ni = 0; ni < NI; ++ni) {
      const int col = bn * BN + wn * (BN / 2) + ni * 16 + lo;
      const float bb = bias[col];
#pragma unroll
      for (int r = 0; r < 4; ++r) {
        const long row = a_row0 + wm * 64 + mi * 16 + hi * 4 + r;
        float vv = acc[mi][ni][r] + bb;
        if constexpr (EPI == EPI_GELU) vv = 0.5f * vv * (1.0f + erff(vv * 0.70710678f));
        if constexpr (EPI == EPI_RES) vv += res[row * Nl + col];
        out[row * Nl + col] = (OT)vv;
      }
    }
  }
}

// ---------------------------------------------------------------- 256x256 8-phase GEMM, 2 barriers/K-tile
// + T1 XCD swizzle (nwg % 8 == 0 for all uses).
template <int EPI, typename OT>
__global__ __launch_bounds__(512) void gemm256(
    const __bf16* __restrict__ A, const __bf16* __restrict__ W,
    const float* __restrict__ bias, OT* __restrict__ out,
    int M, int N, int K) {
  __shared__ char lds[2][2][2][16384];  // [buf][0=A,1=B][half][bytes]
  const int tid = threadIdx.x, l = tid & 63, w = tid >> 6;
  const int wm = w >> 2, wn = w & 3;
  const int lo = l & 15, hi = l >> 4;
  const int gx = gridDim.x;
  int wgid = blockIdx.y * gx + blockIdx.x;
  { const int qq = (gx * gridDim.y) >> 3; wgid = (wgid & 7) * qq + (wgid >> 3); }
  const int bm = wgid / gx, bn = wgid % gx;
  const long Kl = K, Nl = N;
  const long arow0 = (long)bm * 256, brow0 = (long)bn * 256;
  const int nk = K >> 6;

  const int st_row = l >> 2;
  const int st_cb  = ((l & 3) ^ (((l >> 5) & 1) << 1)) * 8;  // bf16 units

  f32x4 acc[8][4];
  const f32x4 fz = {0.f, 0.f, 0.f, 0.f};
#pragma unroll
  for (int i = 0; i < 8; ++i)
#pragma unroll
    for (int j = 0; j < 4; ++j) acc[i][j] = fz;

  auto stageA = [&](int u, int h) {
    char* base = &lds[u & 1][0][h][0];
    const __bf16* src = A + (arow0 + h * 128) * Kl + u * 64;
#pragma unroll
    for (int c = 0; c < 2; ++c) {
      const int s = c * 8 + w;
      gload16(src + (long)((s >> 1) * 16 + st_row) * Kl + ((s & 1) * 32 + st_cb),
              base + s * 1024);
    }
  };
  auto stageB = [&](int u, int h) {
    char* base = &lds[u & 1][1][h][0];
    const __bf16* src = W + (brow0 + h * 128) * Kl + u * 64;
#pragma unroll
    for (int c = 0; c < 2; ++c) {
      const int s = c * 8 + w;
      gload16(src + (long)((s >> 1) * 16 + st_row) * Kl + ((s & 1) * 32 + st_cb),
              base + s * 1024);
    }
  };
  auto rdA = [&](int u, int rr, int cB) -> bf16x8 {
    const char* p = &lds[u & 1][0][rr >> 7][0];
    const int mr = rr & 127;
    return *(const bf16x8*)(p + (mr >> 4) * 2048 + ((cB >> 6) << 10) + (mr & 15) * 64 +
                            ((cB & 63) ^ (((mr >> 3) & 1) << 5)));
  };
  auto rdB = [&](int u, int rr, int cB) -> bf16x8 {
    const char* p = &lds[u & 1][1][rr >> 7][0];
    const int mr = rr & 127;
    return *(const bf16x8*)(p + (mr >> 4) * 2048 + ((cB >> 6) << 10) + (mr & 15) * 64 +
                            ((cB & 63) ^ (((mr >> 3) & 1) << 5)));
  };

  stageA(0, 0); stageA(0, 1); stageB(0, 0); stageB(0, 1);
  stageB(1, 0); stageB(1, 1);
  asm volatile("s_waitcnt vmcnt(4)" ::: "memory");
  __builtin_amdgcn_s_barrier();

  for (int u = 0; u < nk; ++u) {
    bf16x8 bfr[4][2];
    // ---- q0: all B frags + A quad0; stage A(u+1,0); MFMA; B-read fence barrier
#pragma unroll
    for (int nf = 0; nf < 4; ++nf)
#pragma unroll
      for (int kk = 0; kk < 2; ++kk)
        bfr[nf][kk] = rdB(u, wn * 64 + nf * 16 + lo, kk * 64 + 16 * hi);
    {
      bf16x8 af[2][2];
#pragma unroll
      for (int mf = 0; mf < 2; ++mf)
#pragma unroll
        for (int kk = 0; kk < 2; ++kk)
          af[mf][kk] = rdA(u, wm * 128 + mf * 16 + lo, kk * 64 + 16 * hi);
      if (u + 1 < nk) stageA(u + 1, 0);
      asm volatile("s_waitcnt lgkmcnt(0)" ::: "memory");
      __builtin_amdgcn_sched_barrier(0);
      __builtin_amdgcn_s_setprio(1);
#pragma unroll
      for (int mf = 0; mf < 2; ++mf)
#pragma unroll
        for (int nf = 0; nf < 4; ++nf)
#pragma unroll
          for (int kk = 0; kk < 2; ++kk)
            acc[mf][nf] = MFMA16(af[mf][kk], bfr[nf][kk], acc[mf][nf]);
      __builtin_amdgcn_s_setprio(0);
    }
    __builtin_amdgcn_s_barrier();   // all waves' B reads complete; B(u+2) stages now safe

    // ---- q1..q3: A quads; stage A(u+1,1) / B(u+2,0) / B(u+2,1); no barriers
#pragma unroll
    for (int q = 1; q < 4; ++q) {
      bf16x8 af[2][2];
#pragma unroll
      for (int mf = 0; mf < 2; ++mf)
#pragma unroll
        for (int kk = 0; kk < 2; ++kk)
          af[mf][kk] = rdA(u, wm * 128 + (q * 2 + mf) * 16 + lo, kk * 64 + 16 * hi);
      if (q == 1)      { if (u + 1 < nk) stageA(u + 1, 1); }
      else if (q == 2) { if (u + 2 < nk) stageB(u + 2, 0); }
      else             { if (u + 2 < nk) stageB(u + 2, 1); }
      asm volatile("s_waitcnt lgkmcnt(0)" ::: "memory");
      __builtin_amdgcn_sched_barrier(0);
      __builtin_amdgcn_s_setprio(1);
#pragma unroll
      for (int mf = 0; mf < 2; ++mf)
#pragma unroll
        for (int nf = 0; nf < 4; ++nf)
#pragma unroll
          for (int kk = 0; kk < 2; ++kk)
            acc[q * 2 + mf][nf] = MFMA16(af[mf][kk], bfr[nf][kk], acc[q * 2 + mf][nf]);
      __builtin_amdgcn_s_setprio(0);
    }

    // ---- tile boundary: counted vmcnt (tile u+1 landed; B(u+2) may stay in flight)
    if (u + 2 < nk) asm volatile("s_waitcnt vmcnt(4)" ::: "memory");
    else            asm volatile("s_waitcnt vmcnt(0)" ::: "memory");
    __builtin_amdgcn_s_barrier();
  }

#pragma unroll
  for (int mf = 0; mf < 8; ++mf) {
#pragma unroll
    for (int nf = 0; nf < 4; ++nf) {
      const int col = (int)brow0 + wn * 64 + nf * 16 + lo;
      const float bb = bias[col];
#pragma unroll
      for (int r = 0; r < 4; ++r) {
        const long row = arow0 + wm * 128 + mf * 16 + hi * 4 + r;
        float vv = acc[mf][nf][r] + bb;
        if constexpr (EPI == EPI_GELU) vv = 0.5f * vv * (1.0f + erff(vv * 0.70710678f));
        out[row * Nl + col] = (OT)vv;
      }
    }
  }
}

// ---------------------------------------------------------------- 256x256 GEMM, split-K x4 (FFN2), same 2-barrier loop
__global__ __launch_bounds__(512) void gemm256sk(
    const __bf16* __restrict__ A, const __bf16* __restrict__ W,
    __bf16* __restrict__ part, float* __restrict__ fout,
    int M, int N, int Ks, int nk) {
  __shared__ char lds[2][2][2][16384];
  const int tid = threadIdx.x, l = tid & 63, w = tid >> 6;
  const int wm = w >> 2, wn = w & 3;
  const int lo = l & 15, hi = l >> 4;
  const int gx = gridDim.x;
  int wgid = blockIdx.y * gx + blockIdx.x;
  { const int qq = (gx * gridDim.y) >> 3; wgid = (wgid & 7) * qq + (wgid >> 3); }
  const int bm = wgid / gx, bn = wgid % gx, z = blockIdx.z;
  const long Kl = Ks, Nl = N;
  const long arow0 = (long)bm * 256, brow0 = (long)bn * 256;
  const __bf16* As = A + (long)z * nk * 64;
  const __bf16* Ws = W + (long)z * nk * 64;

  const int st_row = l >> 2;
  const int st_cb  = ((l & 3) ^ (((l >> 5) & 1) << 1)) * 8;

  f32x4 acc[8][4];
  const f32x4 fz = {0.f, 0.f, 0.f, 0.f};
#pragma unroll
  for (int i = 0; i < 8; ++i)
#pragma unroll
    for (int j = 0; j < 4; ++j) acc[i][j] = fz;

  auto stageA = [&](int u, int h) {
    char* base = &lds[u & 1][0][h][0];
    const __bf16* src = As + (arow0 + h * 128) * Kl + u * 64;
#pragma unroll
    for (int c = 0; c < 2; ++c) {
      const int s = c * 8 + w;
      gload16(src + (long)((s >> 1) * 16 + st_row) * Kl + ((s & 1) * 32 + st_cb),
              base + s * 1024);
    }
  };
  auto stageB = [&](int u, int h) {
    char* base = &lds[u & 1][1][h][0];
    const __bf16* src = Ws + (brow0 + h * 128) * Kl + u * 64;
#pragma unroll
    for (int c = 0; c < 2; ++c) {
      const int s = c * 8 + w;
      gload16(src + (long)((s >> 1) * 16 + st_row) * Kl + ((s & 1) * 32 + st_cb),
              base + s * 1024);
    }
  };
  auto rdA = [&](int u, int rr, int cB) -> bf16x8 {
    const char* p = &lds[u & 1][0][rr >> 7][0];
    const int mr = rr & 127;
    return *(const bf16x8*)(p + (mr >> 4) * 2048 + ((cB >> 6) << 10) + (mr & 15) * 64 +
                            ((cB & 63) ^ (((mr >> 3) & 1) << 5)));
  };
  auto rdB = [&](int u, int rr, int cB) -> bf16x8 {
    const char* p = &lds[u & 1][1][rr >> 7][0];
    const int mr = rr & 127;
    return *(const bf16x8*)(p + (mr >> 4) * 2048 + ((cB >> 6) << 10) + (mr & 15) * 64 +
                            ((cB & 63) ^ (((mr >> 3) & 1) << 5)));
  };

  stageA(0, 0); stageA(0, 1); stageB(0, 0); stageB(0, 1);
  stageB(1, 0); stageB(1, 1);
  asm volatile("s_waitcnt vmcnt(4)" ::: "memory");
  __builtin_amdgcn_s_barrier();

  for (int u = 0; u < nk; ++u) {
    bf16x8 bfr[4][2];
#pragma unroll
    for (int nf = 0; nf < 4; ++nf)
#pragma unroll
      for (int kk = 0; kk < 2; ++kk)
        bfr[nf][kk] = rdB(u, wn * 64 + nf * 16 + lo, kk * 64 + 16 * hi);
    {
      bf16x8 af[2][2];
#pragma unroll
      for (int mf = 0; mf < 2; ++mf)
#pragma unroll
        for (int kk = 0; kk < 2; ++kk)
          af[mf][kk] = rdA(u, wm * 128 + mf * 16 + lo, kk * 64 + 16 * hi);
      if (u + 1 < nk) stageA(u + 1, 0);
      asm volatile("s_waitcnt lgkmcnt(0)" ::: "memory");
      __builtin_amdgcn_sched_barrier(0);
      __builtin_amdgcn_s_setprio(1);
#pragma unroll
      for (int mf = 0; mf < 2; ++mf)
#pragma unroll
        for (int nf = 0; nf < 4; ++nf)
#pragma unroll
          for (int kk = 0; kk < 2; ++kk)
            acc[mf][nf] = MFMA16(af[mf][kk], bfr[nf][kk], acc[mf][nf]);
      __builtin_amdgcn_s_setprio(0);
    }
    __builtin_amdgcn_s_barrier();   // B-read completion fence

#pragma unroll
    for (int q = 1; q < 4; ++q) {
      bf16x8 af[2][2];
#pragma unroll
      for (int mf = 0; mf < 2; ++mf)
#pragma unroll
        for (int kk = 0; kk < 2; ++kk)
          af[mf][kk] = rdA(u, wm * 128 + (q * 2 + mf) * 16 + lo, kk * 64 + 16 * hi);
      if (q == 1)      { if (u + 1 < nk) stageA(u + 1, 1); }
      else if (q == 2) { if (u + 2 < nk) stageB(u + 2, 0); }
      else             { if (u + 2 < nk) stageB(u + 2, 1); }
      asm volatile("s_waitcnt lgkmcnt(0)" ::: "memory");
      __builtin_amdgcn_sched_barrier(0);
      __builtin_amdgcn_s_setprio(1);
#pragma unroll
      for (int mf = 0; mf < 2; ++mf)
#pragma unroll
        for (int nf = 0; nf < 4; ++nf)
#pragma unroll
          for (int kk = 0; kk < 2; ++kk)
            acc[q * 2 + mf][nf] = MFMA16(af[mf][kk], bfr[nf][kk], acc[q * 2 + mf][nf]);
      __builtin_amdgcn_s_setprio(0);
    }

    if (u + 2 < nk) asm volatile("s_waitcnt vmcnt(4)" ::: "memory");
    else            asm volatile("s_waitcnt vmcnt(0)" ::: "memory");
    __builtin_amdgcn_s_barrier();
  }

  // epilogue: partial store, no bias
  if (z < 3) {
    __bf16* dst = part + (long)z * M * N;
#pragma unroll
    for (int mf = 0; mf < 8; ++mf)
#pragma unroll
      for (int nf = 0; nf < 4; ++nf) {
        const int col = (int)brow0 + wn * 64 + nf * 16 + lo;
#pragma unroll
        for (int r = 0; r < 4; ++r) {
          const long row = arow0 + wm * 128 + mf * 16 + hi * 4 + r;
          dst[row * Nl + col] = (__bf16)acc[mf][nf][r];
        }
      }
  } else {
#pragma unroll
    for (int mf = 0; mf < 8; ++mf)
#pragma unroll
      for (int nf = 0; nf < 4; ++nf) {
        const int col = (int)brow0 + wn * 64 + nf * 16 + lo;
#pragma unroll
        for (int r = 0; r < 4; ++r) {
          const long row = arow0 + wm * 128 + mf * 16 + hi * 4 + r;
          fout[row * Nl + col] = acc[mf][nf][r];
        }
      }
  }
}

// ---------------------------------------------------------------- split-K combine: out = p0+p1+p2 + out + bias + res
__global__ __launch_bounds__(256) void comb_kernel(
    const __bf16* __restrict__ part, const float* __restrict__ bias,
    const float* __restrict__ res, float* __restrict__ out) {
  const long i = ((long)blockIdx.x * 256 + threadIdx.x) * 4;  // [0, 4M)
  const long MN = 4194304;
  float4 o = *(const float4*)&out[i];          // slice-3 partial (f32)
  bf16x4 p0 = *(const bf16x4*)&part[i];
  bf16x4 p1 = *(const bf16x4*)&part[MN + i];
  bf16x4 p2 = *(const bf16x4*)&part[2 * MN + i];
  float4 bb = *(const float4*)&bias[i & 1023];
  float4 rr = *(const float4*)&res[i];
  float4 v;
  v.x = o.x + (float)p0[0] + (float)p1[0] + (float)p2[0] + bb.x + rr.x;
  v.y = o.y + (float)p0[1] + (float)p1[1] + (float)p2[1] + bb.y + rr.y;
  v.z = o.z + (float)p0[2] + (float)p1[2] + (float)p2[2] + bb.z + rr.z;
  v.w = o.w + (float)p0[3] + (float)p1[3] + (float)p2[3] + bb.w + rr.w;
  *(float4*)&out[i] = v;
}

// ---------------------------------------------------------------- Flash attention (causal), packed qkv LD=3072
// Causal pairing + dbuf prefetch + swapped-operand softmax + defer-max (__expf, thr 8)
// + merged dual-tile + diag-only masking. NEW: lane-local defer check — the 2 cross-lane
// shfl_xor max-reduces run ONLY inside the (rare) rescale branch. Safe: __all over
// per-lane 16-max <= mrun+8 bounds every score, so P <= e^8 with mrun unchanged.
__global__ __launch_bounds__(256) void attn_kernel(
    const __bf16* __restrict__ qkv, __bf16* __restrict__ o) {
  __shared__ __bf16 lsK[2][64 * 64];
  __shared__ __bf16 lsV[2][64 * 64];
  __shared__ __bf16 lsP[4][16 * 64];
  const int tid = threadIdx.x, lane = tid & 63, w = tid >> 6;
  const int hi = lane >> 4, lo = lane & 15;
  const int pi = blockIdx.x;                  // 0..15
  const int qtL = pi, qtH = 31 - pi;
  const int b = blockIdx.z, h = blockIdx.y;
  const int qwL = qtL * 64 + w * 16;
  const int qwH = qtH * 64 + w * 16;
  const long base  = (long)b * 2048 * 3072 + h * 64;
  const long obase = (long)b * 2048 * 1024 + h * 64;
  const __bf16* q    = qkv;
  const __bf16* kmat = qkv + 1024;
  const __bf16* v    = qkv + 2048;

  const int ks_row = (lane >> 3);
  const int ks_scol = (((lane & 7) ^ (lane >> 3)) * 8);
  const int vs_key = tid >> 2, vs_db = (tid & 3) * 16;

  bf16x8 aqL[2], aqH[2];
#pragma unroll
  for (int kk = 0; kk < 2; ++kk) {
    aqL[kk] = *(const bf16x8*)&q[base + (long)(qwL + lo) * 3072 + kk * 32 + 8 * hi];
    aqH[kk] = *(const bf16x8*)&q[base + (long)(qwH + lo) * 3072 + kk * 32 + 8 * hi];
  }

  const f32x4 fz = {0.f, 0.f, 0.f, 0.f};
  f32x4 oaccL[4], oaccH[4];
  float mrunL = -1e30f, lrunL = 0.f, mrunH = -1e30f, lrunH = 0.f;
#pragma unroll
  for (int ni = 0; ni < 4; ++ni) { oaccL[ni] = fz; oaccH[ni] = fz; }

  const int nkt = qtH + 1;   // = 32 - pi

  bf16x8 pv0, pv1;
  {
#pragma unroll
    for (int p = 0; p < 2; ++p) {
      const int seg = p * 4 + w;
      gload16(kmat + base + (long)(seg * 8 + ks_row) * 3072 + ks_scol,
              (char*)lsK[0] + seg * 1024);
    }
    const long gv = base + (long)vs_key * 3072 + vs_db;
    pv0 = *(const bf16x8*)&v[gv];
    pv1 = *(const bf16x8*)&v[gv + 8];
    char* lv = (char*)lsV[0];
#pragma unroll
    for (int j = 0; j < 8; ++j) {
      const int d0 = vs_db + j, d1 = vs_db + 8 + j;
      *(__bf16*)(lv + d0 * 128 + ((vs_key * 2) ^ ((d0 & 7) << 4) ^ (((d0 >> 4) & 3) << 5))) = pv0[j];
      *(__bf16*)(lv + d1 * 128 + ((vs_key * 2) ^ ((d1 & 7) << 4) ^ (((d1 >> 4) & 3) << 5))) = pv1[j];
    }
  }
  __syncthreads();

  char* const pbase = (char*)lsP[w] + lo * 128;
  const int swz = (lo & 7) << 4;

  auto finish = [&](f32x4 (&sacc)[4], f32x4 (&oacc)[4], float& mrun, float& lrun,
                    const bf16x8 (&bv)[4][2]) {
    float m0 = fmaxf(fmaxf(sacc[0][0], sacc[0][1]), fmaxf(sacc[0][2], sacc[0][3]));
    float m1 = fmaxf(fmaxf(sacc[1][0], sacc[1][1]), fmaxf(sacc[1][2], sacc[1][3]));
    float m2 = fmaxf(fmaxf(sacc[2][0], sacc[2][1]), fmaxf(sacc[2][2], sacc[2][3]));
    float m3 = fmaxf(fmaxf(sacc[3][0], sacc[3][1]), fmaxf(sacc[3][2], sacc[3][3]));
    float mx = fmaxf(fmaxf(m0, m1), fmaxf(m2, m3));   // lane-local 16-max only

    // T13 defer-max, lane-local check: cross-lane max needed only when rescaling.
    if (!__all(mx - mrun <= 8.0f)) {
      mx = fmaxf(mx, __shfl_xor(mx, 16));
      mx = fmaxf(mx, __shfl_xor(mx, 32));
      const float mnew = fmaxf(mrun, mx);
      const float fac = __expf(mrun - mnew);
      lrun *= fac;
      float facr[4];
#pragma unroll
      for (int r = 0; r < 4; ++r) facr[r] = __shfl(fac, hi * 4 + r);
#pragma unroll
      for (int ni = 0; ni < 4; ++ni)
#pragma unroll
        for (int r = 0; r < 4; ++r) oacc[ni][r] *= facr[r];
      mrun = mnew;
    }

    float sum = 0.f;
#pragma unroll
    for (int ni = 0; ni < 4; ++ni) {
#pragma unroll
      for (int t = 0; t < 2; ++t) {
        const float p0 = __expf(sacc[ni][2 * t]     - mrun);
        const float p1 = __expf(sacc[ni][2 * t + 1] - mrun);
        sum += p0 + p1;
        const unsigned int pk =
            (unsigned int)__builtin_bit_cast(unsigned short, (__bf16)p0) |
            ((unsigned int)__builtin_bit_cast(unsigned short, (__bf16)p1) << 16);
        *(unsigned int*)(pbase + ((32 * ni + 8 * hi + 4 * t) ^ swz)) = pk;
      }
    }
    sum += __shfl_xor(sum, 16);
    sum += __shfl_xor(sum, 32);
    lrun += sum;

#pragma unroll
    for (int kk = 0; kk < 2; ++kk) {
      bf16x8 ap = *(const bf16x8*)(pbase + ((kk * 64 + 16 * hi) ^ swz));
#pragma unroll
      for (int ni = 0; ni < 4; ++ni)
        oacc[ni] = MFMA16(ap, bv[ni][kk], oacc[ni]);
    }
  };

  for (int kt = 0; kt < nkt; ++kt) {
    const int cur = kt & 1;
    const bool more = (kt + 1 < nkt);
    const bool doL = (kt <= qtL);

    if (more) {
#pragma unroll
      for (int p = 0; p < 2; ++p) {
        const int seg = p * 4 + w;
        gload16(kmat + base + (long)((kt + 1) * 64 + seg * 8 + ks_row) * 3072 + ks_scol,
                (char*)lsK[cur ^ 1] + seg * 1024);
      }
      const long gv = base + (long)((kt + 1) * 64 + vs_key) * 3072 + vs_db;
      pv0 = *(const bf16x8*)&v[gv];
      pv1 = *(const bf16x8*)&v[gv + 8];
    }

    bf16x8 bk[4][2];
#pragma unroll
    for (int ni = 0; ni < 4; ++ni) {
      const int row = ni * 16 + lo;
#pragma unroll
      for (int kk = 0; kk < 2; ++kk)
        bk[ni][kk] = *(const bf16x8*)((char*)lsK[cur] + row * 128 +
                                      ((kk * 64 + 16 * hi) ^ ((row & 7) << 4)));
    }

    f32x4 sH[4], sL[4];
#pragma unroll
    for (int ni = 0; ni < 4; ++ni) { sH[ni] = fz; sL[ni] = fz; }
#pragma unroll
    for (int kk = 0; kk < 2; ++kk)
#pragma unroll
      for (int ni = 0; ni < 4; ++ni)
        sH[ni] = MFMA16(bk[ni][kk], aqH[kk], sH[ni]);
    if (doL) {
#pragma unroll
      for (int kk = 0; kk < 2; ++kk)
#pragma unroll
        for (int ni = 0; ni < 4; ++ni)
          sL[ni] = MFMA16(bk[ni][kk], aqL[kk], sL[ni]);
    }

    if (kt == qtH) {
      const int rg = qwH + lo;
#pragma unroll
      for (int ni = 0; ni < 4; ++ni)
#pragma unroll
        for (int r = 0; r < 4; ++r)
          if (kt * 64 + ni * 16 + hi * 4 + r > rg) sH[ni][r] = -1e9f;
    }
    if (doL && kt == qtL) {
      const int rg = qwL + lo;
#pragma unroll
      for (int ni = 0; ni < 4; ++ni)
#pragma unroll
        for (int r = 0; r < 4; ++r)
          if (kt * 64 + ni * 16 + hi * 4 + r > rg) sL[ni][r] = -1e9f;
    }

    bf16x8 bv[4][2];
#pragma unroll
    for (int ni = 0; ni < 4; ++ni) {
      const int d = ni * 16 + lo;
#pragma unroll
      for (int kk = 0; kk < 2; ++kk)
        bv[ni][kk] = *(const bf16x8*)((char*)lsV[cur] + d * 128 +
                                      ((kk * 64 + 16 * hi) ^ ((d & 7) << 4) ^ (((d >> 4) & 3) << 5)));
    }

    finish(sH, oaccH, mrunH, lrunH, bv);
    if (doL) finish(sL, oaccL, mrunL, lrunL, bv);

    if (more) {
      char* lv = (char*)lsV[cur ^ 1];
#pragma unroll
      for (int j = 0; j < 8; ++j) {
        const int d0 = vs_db + j, d1 = vs_db + 8 + j;
        *(__bf16*)(lv + d0 * 128 + ((vs_key * 2) ^ ((d0 & 7) << 4) ^ (((d0 >> 4) & 3) << 5))) = pv0[j];
        *(__bf16*)(lv + d1 * 128 + ((vs_key * 2) ^ ((d1 & 7) << 4) ^ (((d1 >> 4) & 3) << 5))) = pv1[j];
      }
    }
    __syncthreads();
  }

  float lprH[4], lprL[4];
#pragma unroll
  for (int r = 0; r < 4; ++r) {
    lprH[r] = __shfl(lrunH, hi * 4 + r);
    lprL[r] = __shfl(lrunL, hi * 4 + r);
  }
#pragma unroll
  for (int ni = 0; ni < 4; ++ni)
#pragma unroll
    for (int r = 0; r < 4; ++r) {
      const int rowH = qwH + hi * 4 + r;
      const int rowL = qwL + hi * 4 + r;
      o[obase + (long)rowH * 1024 + ni * 16 + lo] = (__bf16)(oaccH[ni][r] / lprH[r]);
      o[obase + (long)rowL * 1024 + ni * 16 + lo] = (__bf16)(oaccL[ni][r] / lprL[r]);
    }
}

// ---------------------------------------------------------------- launcher
extern "C" void kernel_launch(void* const* d_in, const int* in_sizes, int n_in,
                              void* d_out, int out_size, void* d_ws, size_t ws_size,
                              hipStream_t stream) {
  const float* x    = (const float*)d_in[0];
  const float* fr   = (const float*)d_in[1];
  const float* ln1g = (const float*)d_in[3];
  const float* ln1b = (const float*)d_in[4];
  const float* Wq   = (const float*)d_in[5];
  const float* bq   = (const float*)d_in[6];
  const float* Wk   = (const float*)d_in[7];
  const float* bk   = (const float*)d_in[8];
  const float* Wv   = (const float*)d_in[9];
  const float* bv   = (const float*)d_in[10];
  const float* Wo   = (const float*)d_in[11];
  const float* bo   = (const float*)d_in[12];
  const float* ln2g = (const float*)d_in[13];
  const float* ln2b = (const float*)d_in[14];
  const float* W1   = (const float*)d_in[15];
  const float* b1   = (const float*)d_in[16];
  const float* W2   = (const float*)d_in[17];
  const float* b2   = (const float*)d_in[18];
  float* out = (float*)d_out;

  char* ws = (char*)d_ws;
  const size_t SZ = 8388608;  // 8 MB
  __bf16* xn   = (__bf16*)(ws + 0);              // 8 MB
  __bf16* qkv  = (__bf16*)(ws + 1 * SZ);         // 24 MB (8..32)
  __bf16* attn = (__bf16*)(ws + 0);              // reuse xn
  float*  bqkv = (float*)(ws + 4 * SZ);          // 12 KB, dead before x2 written
  float*  x2   = (float*)(ws + 4 * SZ);          // 16 MB f32 (32..48)
  __bf16* hin  = (__bf16*)(ws + 6 * SZ);         // 8 MB (48..56)
  __bf16* hmid = (__bf16*)(ws + 0);              // 32 MB (0..32), qkv/attn dead
  char* wb = ws + 7 * SZ;                        // bf16 weights, 24 MB (56..80), contiguous
  __bf16* Wqkvb = (__bf16*)(wb + 0);             // 6 MB: Wq|Wk|Wv packed along N
  __bf16* Wob   = (__bf16*)(wb + 6 * 1048576);
  __bf16* W1b   = (__bf16*)(wb + 8 * 1048576);
  __bf16* W2b   = (__bf16*)(wb + 16 * 1048576);
  // split-K partials (FFN2): 3 x 8 MB bf16 at 48..72 — hin/Wqkvb/Wob/W1b are dead
  // by the time gemm256sk runs; cvt6 re-converts weights every launch.
  __bf16* part  = (__bf16*)(ws + 6 * SZ);

  const int M = 4096, D = 1024, FF = 4096;
  dim3 blk(256), blk5(512);

  cvt6_kernel<<<6144, blk, 0, stream>>>(Wq, Wk, Wv, Wo, W1, W2, Wqkvb);
  pack3_kernel<<<12, blk, 0, stream>>>(bq, bk, bv, bqkv);

  ln_kernel<<<4096, blk, 0, stream>>>(x, ln1g, ln1b, xn);
  gemm256<EPI_NONE, __bf16><<<dim3(3072 / 256, M / 256), blk5, 0, stream>>>(
      xn, Wqkvb, bqkv, qkv, M, 3072, D);
  rope_kernel<<<dim3(2048, 2), blk, 0, stream>>>(qkv, fr);
  attn_kernel<<<dim3(16, 16, 2), blk, 0, stream>>>(qkv, attn);
  gemm_bt<EPI_RES, float, 64><<<dim3(D / 64, M / 128), blk, 0, stream>>>(
      attn, Wob, bo, x, x2, M, D, D);
  ln_kernel<<<4096, blk, 0, stream>>>(x2, ln2g, ln2b, hin);
  gemm256<EPI_GELU, __bf16><<<dim3(FF / 256, M / 256), blk5, 0, stream>>>(
      hin, W1b, b1, hmid, M, FF, D);
  gemm256sk<<<dim3(D / 256, M / 256, 4), blk5, 0, stream>>>(
      hmid, W2b, part, out, M, D, FF, 16);
  comb_kernel<<<4096, blk, 0, stream>>>(part, b2, x2, out);
}

// Round 25
// 233.107 us; speedup vs baseline: 1.1108x; 1.1108x over previous
//
#include <hip/hip_runtime.h>
#include <hip/hip_bf16.h>

typedef __bf16 bf16x8 __attribute__((ext_vector_type(8)));
typedef __bf16 bf16x4 __attribute__((ext_vector_type(4)));
typedef float  f32x4  __attribute__((ext_vector_type(4)));

#define MFMA16(a, b, c) __builtin_amdgcn_mfma_f32_16x16x32_bf16((a), (b), (c), 0, 0, 0)

__device__ __forceinline__ void gload16(const void* g, void* l) {
  __builtin_amdgcn_global_load_lds(
      (const __attribute__((address_space(1))) unsigned int*)g,
      (__attribute__((address_space(3))) unsigned int*)l, 16, 0, 0);
}

// ---------------------------------------------------------------- f32 -> bf16 pack, all 6 weights in one launch
__global__ __launch_bounds__(256) void cvt6_kernel(
    const float* __restrict__ wq, const float* __restrict__ wk,
    const float* __restrict__ wv, const float* __restrict__ wo,
    const float* __restrict__ w1, const float* __restrict__ w2,
    __bf16* __restrict__ dst) {
  const long i = ((long)blockIdx.x * 256 + threadIdx.x) * 8;  // [0, 12M)
  const long M1 = 1048576;
  const float* src;
  long off;
  if      (i < 1 * M1) { src = wq; off = i; }
  else if (i < 2 * M1) { src = wk; off = i - 1 * M1; }
  else if (i < 3 * M1) { src = wv; off = i - 2 * M1; }
  else if (i < 4 * M1) { src = wo; off = i - 3 * M1; }
  else if (i < 8 * M1) { src = w1; off = i - 4 * M1; }
  else                 { src = w2; off = i - 8 * M1; }
  float4 a = *(const float4*)&src[off];
  float4 b = *(const float4*)&src[off + 4];
  bf16x8 o;
  o[0] = (__bf16)a.x; o[1] = (__bf16)a.y; o[2] = (__bf16)a.z; o[3] = (__bf16)a.w;
  o[4] = (__bf16)b.x; o[5] = (__bf16)b.y; o[6] = (__bf16)b.z; o[7] = (__bf16)b.w;
  *(bf16x8*)&dst[i] = o;
}

// pack 3 bias vectors (1024 each) into one f32[3072]
__global__ __launch_bounds__(256) void pack3_kernel(
    const float* __restrict__ a, const float* __restrict__ b,
    const float* __restrict__ c, float* __restrict__ o) {
  const int i = blockIdx.x * 256 + threadIdx.x;
  o[i] = i < 1024 ? a[i] : (i < 2048 ? b[i - 1024] : c[i - 2048]);
}

// ---------------------------------------------------------------- LayerNorm (f32 in -> bf16 out)
__global__ __launch_bounds__(256) void ln_kernel(
    const float* __restrict__ in, const float* __restrict__ gg,
    const float* __restrict__ bb, __bf16* __restrict__ out) {
  __shared__ float sred[8];
  const long row = blockIdx.x;
  const int tid = threadIdx.x;
  float4 u = *(const float4*)&in[row * 1024 + tid * 4];
  float f[4] = {u.x, u.y, u.z, u.w};
  float s = 0.f, sq = 0.f;
#pragma unroll
  for (int j = 0; j < 4; ++j) { s += f[j]; sq += f[j] * f[j]; }
#pragma unroll
  for (int d = 32; d; d >>= 1) { s += __shfl_xor(s, d); sq += __shfl_xor(sq, d); }
  const int w = tid >> 6;
  if ((tid & 63) == 0) { sred[w * 2] = s; sred[w * 2 + 1] = sq; }
  __syncthreads();
  s  = sred[0] + sred[2] + sred[4] + sred[6];
  sq = sred[1] + sred[3] + sred[5] + sred[7];
  const float mean = s * (1.f / 1024.f);
  const float var  = sq * (1.f / 1024.f) - mean * mean;
  const float rstd = rsqrtf(var + 1e-5f);
  float4 gv = *(const float4*)&gg[tid * 4];
  float4 bv = *(const float4*)&bb[tid * 4];
  bf16x4 ov;
  ov[0] = (__bf16)((f[0] - mean) * rstd * gv.x + bv.x);
  ov[1] = (__bf16)((f[1] - mean) * rstd * gv.y + bv.y);
  ov[2] = (__bf16)((f[2] - mean) * rstd * gv.z + bv.z);
  ov[3] = (__bf16)((f[3] - mean) * rstd * gv.w + bv.w);
  *(bf16x4*)&out[row * 1024 + tid * 4] = ov;
}

// ---------------------------------------------------------------- RoPE (in place on packed qkv, LD=3072), bf16x8
__global__ __launch_bounds__(256) void rope_kernel(
    __bf16* __restrict__ qkv, const float* __restrict__ freqs) {
  const int idx = blockIdx.x * 256 + threadIdx.x;   // [0, 4096*16*8)
  const int isq = (blockIdx.y == 0);
  __bf16* p = qkv + (isq ? 0 : 1024);
  const float scale = isq ? 0.125f : 1.0f;
  const int token = idx >> 7;
  const int wi = idx & 127;
  const int head = wi >> 3, i4 = wi & 7;
  const int spos = token & 2047;
  float4 fv = *(const float4*)&freqs[spos * 32 + i4 * 4];
  const long off = (long)token * 3072 + head * 64 + i4 * 8;
  bf16x8 u = *(bf16x8*)&p[off];
  float sn[4], cs[4];
  sincosf(fv.x, &sn[0], &cs[0]);
  sincosf(fv.y, &sn[1], &cs[1]);
  sincosf(fv.z, &sn[2], &cs[2]);
  sincosf(fv.w, &sn[3], &cs[3]);
  bf16x8 ov;
#pragma unroll
  for (int j = 0; j < 4; ++j) {
    const float x0 = (float)u[2 * j], x1 = (float)u[2 * j + 1];
    ov[2 * j]     = (__bf16)((x0 * cs[j] - x1 * sn[j]) * scale);
    ov[2 * j + 1] = (__bf16)((x1 * cs[j] + x0 * sn[j]) * scale);
  }
  *(bf16x8*)&p[off] = ov;
}

// ---------------------------------------------------------------- GEMM 128x64 tile, 3-buffer 2-deep pipeline
// + T2 LDS XOR-swizzle + T1 XCD swizzle. Counted vmcnt + raw barrier. (Wo-proj only now.)
enum { EPI_NONE = 0, EPI_GELU = 1, EPI_RES = 2 };

template <int EPI, typename OT, int BN>
__global__ __launch_bounds__(256) void gemm_bt(
    const __bf16* __restrict__ A, const __bf16* __restrict__ W,
    const float* __restrict__ bias, const float* __restrict__ res,
    OT* __restrict__ out, int M, int N, int K) {
  static_assert(BN == 64, "vmcnt count hardcoded for 6 loads/stage");
  constexpr int NI = BN / 32;          // fragments per wave along N
  __shared__ __bf16 lsA[3][128 * 64];
  __shared__ __bf16 lsB[3][BN * 64];
  const int tid = threadIdx.x, lane = tid & 63, w = tid >> 6;
  const int lo = lane & 15, hi = lane >> 4;
  const int gx = gridDim.x;
  int wgid = blockIdx.y * gx + blockIdx.x;
  { const int qq = (gx * gridDim.y) >> 3; wgid = (wgid & 7) * qq + (wgid >> 3); }
  const int bm = wgid / gx, bn = wgid % gx;
  const int wm = w >> 1, wn = w & 1;
  const long Kl = K, Nl = N;
  const long a_row0 = (long)bm * 128, b_row0 = (long)bn * BN;
  const int pr_row = lane >> 3;
  const int pr_scol = ((lane & 7) ^ (lane >> 3)) * 8;   // T2 inverse-swizzled source col

  auto stage = [&](int t, int buf) {   // 6 gload16 per wave (4 A + 2 B), linear LDS dest
    const int kt = t * 64;
#pragma unroll
    for (int p = 0; p < 4; ++p) {
      const int seg = p * 4 + w;
      const int row = seg * 8 + pr_row;
      gload16(A + (a_row0 + row) * Kl + kt + pr_scol, (char*)lsA[buf] + seg * 1024);
    }
#pragma unroll
    for (int p = 0; p < BN / 32; ++p) {
      const int seg = p * 4 + w;
      const int row = seg * 8 + pr_row;
      gload16(W + (b_row0 + row) * Kl + kt + pr_scol, (char*)lsB[buf] + seg * 1024);
    }
  };

  f32x4 acc[4][NI];
  const f32x4 fz = {0.f, 0.f, 0.f, 0.f};
#pragma unroll
  for (int i = 0; i < 4; ++i)
#pragma unroll
    for (int j = 0; j < NI; ++j) acc[i][j] = fz;

  const int nk = K >> 6;
  stage(0, 0);
  stage(1, 1);

  for (int n = 0; n < nk; ++n) {
    if (n + 1 < nk) asm volatile("s_waitcnt vmcnt(6)" ::: "memory");
    else            asm volatile("s_waitcnt vmcnt(0)" ::: "memory");
    __builtin_amdgcn_s_barrier();
    if (n + 2 < nk) stage(n + 2, (n + 2) % 3);
    const int cur = n % 3;
#pragma unroll
    for (int kk = 0; kk < 2; ++kk) {
      bf16x8 af[4], bfr[NI];
#pragma unroll
      for (int i = 0; i < 4; ++i) {
        const int row = wm * 64 + i * 16 + lo;
        af[i] = *(const bf16x8*)((char*)lsA[cur] + row * 128 +
                                 ((kk * 64 + 16 * hi) ^ ((row & 7) << 4)));
      }
#pragma unroll
      for (int i = 0; i < NI; ++i) {
        const int row = wn * (BN / 2) + i * 16 + lo;
        bfr[i] = *(const bf16x8*)((char*)lsB[cur] + row * 128 +
                                  ((kk * 64 + 16 * hi) ^ ((row & 7) << 4)));
      }
#pragma unroll
      for (int mi = 0; mi < 4; ++mi)
#pragma unroll
        for (int ni = 0; ni < NI; ++ni)
          acc[mi][ni] = MFMA16(af[mi], bfr[ni], acc[mi][ni]);
    }
  }

#pragma unroll
  for (int mi = 0; mi < 4; ++mi) {
#pragma unroll
    for (int ni = 0; ni < NI; ++ni) {
      const int col = bn * BN + wn * (BN / 2) + ni * 16 + lo;
      const float bb = bias[col];
#pragma unroll
      for (int r = 0; r < 4; ++r) {
        const long row = a_row0 + wm * 64 + mi * 16 + hi * 4 + r;
        float vv = acc[mi][ni][r] + bb;
        if constexpr (EPI == EPI_GELU) vv = 0.5f * vv * (1.0f + erff(vv * 0.70710678f));
        if constexpr (EPI == EPI_RES) vv += res[row * Nl + col];
        out[row * Nl + col] = (OT)vv;
      }
    }
  }
}

// ---------------------------------------------------------------- 256x256 8-phase GEMM, 2 barriers/K-tile
// + T1 XCD swizzle (nwg % 8 == 0 for all uses).
template <int EPI, typename OT>
__global__ __launch_bounds__(512) void gemm256(
    const __bf16* __restrict__ A, const __bf16* __restrict__ W,
    const float* __restrict__ bias, OT* __restrict__ out,
    int M, int N, int K) {
  __shared__ char lds[2][2][2][16384];  // [buf][0=A,1=B][half][bytes]
  const int tid = threadIdx.x, l = tid & 63, w = tid >> 6;
  const int wm = w >> 2, wn = w & 3;
  const int lo = l & 15, hi = l >> 4;
  const int gx = gridDim.x;
  int wgid = blockIdx.y * gx + blockIdx.x;
  { const int qq = (gx * gridDim.y) >> 3; wgid = (wgid & 7) * qq + (wgid >> 3); }
  const int bm = wgid / gx, bn = wgid % gx;
  const long Kl = K, Nl = N;
  const long arow0 = (long)bm * 256, brow0 = (long)bn * 256;
  const int nk = K >> 6;

  const int st_row = l >> 2;
  const int st_cb  = ((l & 3) ^ (((l >> 5) & 1) << 1)) * 8;  // bf16 units

  f32x4 acc[8][4];
  const f32x4 fz = {0.f, 0.f, 0.f, 0.f};
#pragma unroll
  for (int i = 0; i < 8; ++i)
#pragma unroll
    for (int j = 0; j < 4; ++j) acc[i][j] = fz;

  auto stageA = [&](int u, int h) {
    char* base = &lds[u & 1][0][h][0];
    const __bf16* src = A + (arow0 + h * 128) * Kl + u * 64;
#pragma unroll
    for (int c = 0; c < 2; ++c) {
      const int s = c * 8 + w;
      gload16(src + (long)((s >> 1) * 16 + st_row) * Kl + ((s & 1) * 32 + st_cb),
              base + s * 1024);
    }
  };
  auto stageB = [&](int u, int h) {
    char* base = &lds[u & 1][1][h][0];
    const __bf16* src = W + (brow0 + h * 128) * Kl + u * 64;
#pragma unroll
    for (int c = 0; c < 2; ++c) {
      const int s = c * 8 + w;
      gload16(src + (long)((s >> 1) * 16 + st_row) * Kl + ((s & 1) * 32 + st_cb),
              base + s * 1024);
    }
  };
  auto rdA = [&](int u, int rr, int cB) -> bf16x8 {
    const char* p = &lds[u & 1][0][rr >> 7][0];
    const int mr = rr & 127;
    return *(const bf16x8*)(p + (mr >> 4) * 2048 + ((cB >> 6) << 10) + (mr & 15) * 64 +
                            ((cB & 63) ^ (((mr >> 3) & 1) << 5)));
  };
  auto rdB = [&](int u, int rr, int cB) -> bf16x8 {
    const char* p = &lds[u & 1][1][rr >> 7][0];
    const int mr = rr & 127;
    return *(const bf16x8*)(p + (mr >> 4) * 2048 + ((cB >> 6) << 10) + (mr & 15) * 64 +
                            ((cB & 63) ^ (((mr >> 3) & 1) << 5)));
  };

  stageA(0, 0); stageA(0, 1); stageB(0, 0); stageB(0, 1);
  stageB(1, 0); stageB(1, 1);
  asm volatile("s_waitcnt vmcnt(4)" ::: "memory");
  __builtin_amdgcn_s_barrier();

  for (int u = 0; u < nk; ++u) {
    bf16x8 bfr[4][2];
    // ---- q0: all B frags + A quad0; stage A(u+1,0); MFMA; B-read fence barrier
#pragma unroll
    for (int nf = 0; nf < 4; ++nf)
#pragma unroll
      for (int kk = 0; kk < 2; ++kk)
        bfr[nf][kk] = rdB(u, wn * 64 + nf * 16 + lo, kk * 64 + 16 * hi);
    {
      bf16x8 af[2][2];
#pragma unroll
      for (int mf = 0; mf < 2; ++mf)
#pragma unroll
        for (int kk = 0; kk < 2; ++kk)
          af[mf][kk] = rdA(u, wm * 128 + mf * 16 + lo, kk * 64 + 16 * hi);
      if (u + 1 < nk) stageA(u + 1, 0);
      asm volatile("s_waitcnt lgkmcnt(0)" ::: "memory");
      __builtin_amdgcn_sched_barrier(0);
      __builtin_amdgcn_s_setprio(1);
#pragma unroll
      for (int mf = 0; mf < 2; ++mf)
#pragma unroll
        for (int nf = 0; nf < 4; ++nf)
#pragma unroll
          for (int kk = 0; kk < 2; ++kk)
            acc[mf][nf] = MFMA16(af[mf][kk], bfr[nf][kk], acc[mf][nf]);
      __builtin_amdgcn_s_setprio(0);
    }
    __builtin_amdgcn_s_barrier();   // all waves' B reads complete; B(u+2) stages now safe

    // ---- q1..q3: A quads; stage A(u+1,1) / B(u+2,0) / B(u+2,1); no barriers
#pragma unroll
    for (int q = 1; q < 4; ++q) {
      bf16x8 af[2][2];
#pragma unroll
      for (int mf = 0; mf < 2; ++mf)
#pragma unroll
        for (int kk = 0; kk < 2; ++kk)
          af[mf][kk] = rdA(u, wm * 128 + (q * 2 + mf) * 16 + lo, kk * 64 + 16 * hi);
      if (q == 1)      { if (u + 1 < nk) stageA(u + 1, 1); }
      else if (q == 2) { if (u + 2 < nk) stageB(u + 2, 0); }
      else             { if (u + 2 < nk) stageB(u + 2, 1); }
      asm volatile("s_waitcnt lgkmcnt(0)" ::: "memory");
      __builtin_amdgcn_sched_barrier(0);
      __builtin_amdgcn_s_setprio(1);
#pragma unroll
      for (int mf = 0; mf < 2; ++mf)
#pragma unroll
        for (int nf = 0; nf < 4; ++nf)
#pragma unroll
          for (int kk = 0; kk < 2; ++kk)
            acc[q * 2 + mf][nf] = MFMA16(af[mf][kk], bfr[nf][kk], acc[q * 2 + mf][nf]);
      __builtin_amdgcn_s_setprio(0);
    }

    // ---- tile boundary: counted vmcnt (tile u+1 landed; B(u+2) may stay in flight)
    if (u + 2 < nk) asm volatile("s_waitcnt vmcnt(4)" ::: "memory");
    else            asm volatile("s_waitcnt vmcnt(0)" ::: "memory");
    __builtin_amdgcn_s_barrier();
  }

#pragma unroll
  for (int mf = 0; mf < 8; ++mf) {
#pragma unroll
    for (int nf = 0; nf < 4; ++nf) {
      const int col = (int)brow0 + wn * 64 + nf * 16 + lo;
      const float bb = bias[col];
#pragma unroll
      for (int r = 0; r < 4; ++r) {
        const long row = arow0 + wm * 128 + mf * 16 + hi * 4 + r;
        float vv = acc[mf][nf][r] + bb;
        if constexpr (EPI == EPI_GELU) vv = 0.5f * vv * (1.0f + erff(vv * 0.70710678f));
        out[row * Nl + col] = (OT)vv;
      }
    }
  }
}

// ---------------------------------------------------------------- 256x256 GEMM, split-K x4 (FFN2), same 2-barrier loop
__global__ __launch_bounds__(512) void gemm256sk(
    const __bf16* __restrict__ A, const __bf16* __restrict__ W,
    __bf16* __restrict__ part, float* __restrict__ fout,
    int M, int N, int Ks, int nk) {
  __shared__ char lds[2][2][2][16384];
  const int tid = threadIdx.x, l = tid & 63, w = tid >> 6;
  const int wm = w >> 2, wn = w & 3;
  const int lo = l & 15, hi = l >> 4;
  const int gx = gridDim.x;
  int wgid = blockIdx.y * gx + blockIdx.x;
  { const int qq = (gx * gridDim.y) >> 3; wgid = (wgid & 7) * qq + (wgid >> 3); }
  const int bm = wgid / gx, bn = wgid % gx, z = blockIdx.z;
  const long Kl = Ks, Nl = N;
  const long arow0 = (long)bm * 256, brow0 = (long)bn * 256;
  const __bf16* As = A + (long)z * nk * 64;
  const __bf16* Ws = W + (long)z * nk * 64;

  const int st_row = l >> 2;
  const int st_cb  = ((l & 3) ^ (((l >> 5) & 1) << 1)) * 8;

  f32x4 acc[8][4];
  const f32x4 fz = {0.f, 0.f, 0.f, 0.f};
#pragma unroll
  for (int i = 0; i < 8; ++i)
#pragma unroll
    for (int j = 0; j < 4; ++j) acc[i][j] = fz;

  auto stageA = [&](int u, int h) {
    char* base = &lds[u & 1][0][h][0];
    const __bf16* src = As + (arow0 + h * 128) * Kl + u * 64;
#pragma unroll
    for (int c = 0; c < 2; ++c) {
      const int s = c * 8 + w;
      gload16(src + (long)((s >> 1) * 16 + st_row) * Kl + ((s & 1) * 32 + st_cb),
              base + s * 1024);
    }
  };
  auto stageB = [&](int u, int h) {
    char* base = &lds[u & 1][1][h][0];
    const __bf16* src = Ws + (brow0 + h * 128) * Kl + u * 64;
#pragma unroll
    for (int c = 0; c < 2; ++c) {
      const int s = c * 8 + w;
      gload16(src + (long)((s >> 1) * 16 + st_row) * Kl + ((s & 1) * 32 + st_cb),
              base + s * 1024);
    }
  };
  auto rdA = [&](int u, int rr, int cB) -> bf16x8 {
    const char* p = &lds[u & 1][0][rr >> 7][0];
    const int mr = rr & 127;
    return *(const bf16x8*)(p + (mr >> 4) * 2048 + ((cB >> 6) << 10) + (mr & 15) * 64 +
                            ((cB & 63) ^ (((mr >> 3) & 1) << 5)));
  };
  auto rdB = [&](int u, int rr, int cB) -> bf16x8 {
    const char* p = &lds[u & 1][1][rr >> 7][0];
    const int mr = rr & 127;
    return *(const bf16x8*)(p + (mr >> 4) * 2048 + ((cB >> 6) << 10) + (mr & 15) * 64 +
                            ((cB & 63) ^ (((mr >> 3) & 1) << 5)));
  };

  stageA(0, 0); stageA(0, 1); stageB(0, 0); stageB(0, 1);
  stageB(1, 0); stageB(1, 1);
  asm volatile("s_waitcnt vmcnt(4)" ::: "memory");
  __builtin_amdgcn_s_barrier();

  for (int u = 0; u < nk; ++u) {
    bf16x8 bfr[4][2];
#pragma unroll
    for (int nf = 0; nf < 4; ++nf)
#pragma unroll
      for (int kk = 0; kk < 2; ++kk)
        bfr[nf][kk] = rdB(u, wn * 64 + nf * 16 + lo, kk * 64 + 16 * hi);
    {
      bf16x8 af[2][2];
#pragma unroll
      for (int mf = 0; mf < 2; ++mf)
#pragma unroll
        for (int kk = 0; kk < 2; ++kk)
          af[mf][kk] = rdA(u, wm * 128 + mf * 16 + lo, kk * 64 + 16 * hi);
      if (u + 1 < nk) stageA(u + 1, 0);
      asm volatile("s_waitcnt lgkmcnt(0)" ::: "memory");
      __builtin_amdgcn_sched_barrier(0);
      __builtin_amdgcn_s_setprio(1);
#pragma unroll
      for (int mf = 0; mf < 2; ++mf)
#pragma unroll
        for (int nf = 0; nf < 4; ++nf)
#pragma unroll
          for (int kk = 0; kk < 2; ++kk)
            acc[mf][nf] = MFMA16(af[mf][kk], bfr[nf][kk], acc[mf][nf]);
      __builtin_amdgcn_s_setprio(0);
    }
    __builtin_amdgcn_s_barrier();   // B-read completion fence

#pragma unroll
    for (int q = 1; q < 4; ++q) {
      bf16x8 af[2][2];
#pragma unroll
      for (int mf = 0; mf < 2; ++mf)
#pragma unroll
        for (int kk = 0; kk < 2; ++kk)
          af[mf][kk] = rdA(u, wm * 128 + (q * 2 + mf) * 16 + lo, kk * 64 + 16 * hi);
      if (q == 1)      { if (u + 1 < nk) stageA(u + 1, 1); }
      else if (q == 2) { if (u + 2 < nk) stageB(u + 2, 0); }
      else             { if (u + 2 < nk) stageB(u + 2, 1); }
      asm volatile("s_waitcnt lgkmcnt(0)" ::: "memory");
      __builtin_amdgcn_sched_barrier(0);
      __builtin_amdgcn_s_setprio(1);
#pragma unroll
      for (int mf = 0; mf < 2; ++mf)
#pragma unroll
        for (int nf = 0; nf < 4; ++nf)
#pragma unroll
          for (int kk = 0; kk < 2; ++kk)
            acc[q * 2 + mf][nf] = MFMA16(af[mf][kk], bfr[nf][kk], acc[q * 2 + mf][nf]);
      __builtin_amdgcn_s_setprio(0);
    }

    if (u + 2 < nk) asm volatile("s_waitcnt vmcnt(4)" ::: "memory");
    else            asm volatile("s_waitcnt vmcnt(0)" ::: "memory");
    __builtin_amdgcn_s_barrier();
  }

  // epilogue: partial store, no bias
  if (z < 3) {
    __bf16* dst = part + (long)z * M * N;
#pragma unroll
    for (int mf = 0; mf < 8; ++mf)
#pragma unroll
      for (int nf = 0; nf < 4; ++nf) {
        const int col = (int)brow0 + wn * 64 + nf * 16 + lo;
#pragma unroll
        for (int r = 0; r < 4; ++r) {
          const long row = arow0 + wm * 128 + mf * 16 + hi * 4 + r;
          dst[row * Nl + col] = (__bf16)acc[mf][nf][r];
        }
      }
  } else {
#pragma unroll
    for (int mf = 0; mf < 8; ++mf)
#pragma unroll
      for (int nf = 0; nf < 4; ++nf) {
        const int col = (int)brow0 + wn * 64 + nf * 16 + lo;
#pragma unroll
        for (int r = 0; r < 4; ++r) {
          const long row = arow0 + wm * 128 + mf * 16 + hi * 4 + r;
          fout[row * Nl + col] = acc[mf][nf][r];
        }
      }
  }
}

// ---------------------------------------------------------------- split-K combine: out = p0+p1+p2 + out + bias + res
__global__ __launch_bounds__(256) void comb_kernel(
    const __bf16* __restrict__ part, const float* __restrict__ bias,
    const float* __restrict__ res, float* __restrict__ out) {
  const long i = ((long)blockIdx.x * 256 + threadIdx.x) * 4;  // [0, 4M)
  const long MN = 4194304;
  float4 o = *(const float4*)&out[i];          // slice-3 partial (f32)
  bf16x4 p0 = *(const bf16x4*)&part[i];
  bf16x4 p1 = *(const bf16x4*)&part[MN + i];
  bf16x4 p2 = *(const bf16x4*)&part[2 * MN + i];
  float4 bb = *(const float4*)&bias[i & 1023];
  float4 rr = *(const float4*)&res[i];
  float4 v;
  v.x = o.x + (float)p0[0] + (float)p1[0] + (float)p2[0] + bb.x + rr.x;
  v.y = o.y + (float)p0[1] + (float)p1[1] + (float)p2[1] + bb.y + rr.y;
  v.z = o.z + (float)p0[2] + (float)p1[2] + (float)p2[2] + bb.z + rr.z;
  v.w = o.w + (float)p0[3] + (float)p1[3] + (float)p2[3] + bb.w + rr.w;
  *(float4*)&out[i] = v;
}

// ---------------------------------------------------------------- Flash attention (causal), packed qkv LD=3072
// Causal pairing + dbuf prefetch + swapped-operand softmax + defer-max (__expf, thr 8)
// + merged dual-tile + diag-only masking. R23 config (VGPR=128, the occupancy cliff);
// R22 (dual-P, 136 VGPR) and R24 (lane-local defer, 140 VGPR) both halved occupancy
// and regressed ~40% — do not add register pressure to this kernel.
__global__ __launch_bounds__(256) void attn_kernel(
    const __bf16* __restrict__ qkv, __bf16* __restrict__ o) {
  __shared__ __bf16 lsK[2][64 * 64];
  __shared__ __bf16 lsV[2][64 * 64];
  __shared__ __bf16 lsP[4][16 * 64];
  const int tid = threadIdx.x, lane = tid & 63, w = tid >> 6;
  const int hi = lane >> 4, lo = lane & 15;
  const int pi = blockIdx.x;                  // 0..15
  const int qtL = pi, qtH = 31 - pi;
  const int b = blockIdx.z, h = blockIdx.y;
  const int qwL = qtL * 64 + w * 16;
  const int qwH = qtH * 64 + w * 16;
  const long base  = (long)b * 2048 * 3072 + h * 64;
  const long obase = (long)b * 2048 * 1024 + h * 64;
  const __bf16* q    = qkv;
  const __bf16* kmat = qkv + 1024;
  const __bf16* v    = qkv + 2048;

  const int ks_row = (lane >> 3);
  const int ks_scol = (((lane & 7) ^ (lane >> 3)) * 8);
  const int vs_key = tid >> 2, vs_db = (tid & 3) * 16;

  bf16x8 aqL[2], aqH[2];
#pragma unroll
  for (int kk = 0; kk < 2; ++kk) {
    aqL[kk] = *(const bf16x8*)&q[base + (long)(qwL + lo) * 3072 + kk * 32 + 8 * hi];
    aqH[kk] = *(const bf16x8*)&q[base + (long)(qwH + lo) * 3072 + kk * 32 + 8 * hi];
  }

  const f32x4 fz = {0.f, 0.f, 0.f, 0.f};
  f32x4 oaccL[4], oaccH[4];
  float mrunL = -1e30f, lrunL = 0.f, mrunH = -1e30f, lrunH = 0.f;
#pragma unroll
  for (int ni = 0; ni < 4; ++ni) { oaccL[ni] = fz; oaccH[ni] = fz; }

  const int nkt = qtH + 1;   // = 32 - pi

  bf16x8 pv0, pv1;
  {
#pragma unroll
    for (int p = 0; p < 2; ++p) {
      const int seg = p * 4 + w;
      gload16(kmat + base + (long)(seg * 8 + ks_row) * 3072 + ks_scol,
              (char*)lsK[0] + seg * 1024);
    }
    const long gv = base + (long)vs_key * 3072 + vs_db;
    pv0 = *(const bf16x8*)&v[gv];
    pv1 = *(const bf16x8*)&v[gv + 8];
    char* lv = (char*)lsV[0];
#pragma unroll
    for (int j = 0; j < 8; ++j) {
      const int d0 = vs_db + j, d1 = vs_db + 8 + j;
      *(__bf16*)(lv + d0 * 128 + ((vs_key * 2) ^ ((d0 & 7) << 4) ^ (((d0 >> 4) & 3) << 5))) = pv0[j];
      *(__bf16*)(lv + d1 * 128 + ((vs_key * 2) ^ ((d1 & 7) << 4) ^ (((d1 >> 4) & 3) << 5))) = pv1[j];
    }
  }
  __syncthreads();

  char* const pbase = (char*)lsP[w] + lo * 128;
  const int swz = (lo & 7) << 4;

  auto finish = [&](f32x4 (&sacc)[4], f32x4 (&oacc)[4], float& mrun, float& lrun,
                    const bf16x8 (&bv)[4][2]) {
    float m0 = fmaxf(fmaxf(sacc[0][0], sacc[0][1]), fmaxf(sacc[0][2], sacc[0][3]));
    float m1 = fmaxf(fmaxf(sacc[1][0], sacc[1][1]), fmaxf(sacc[1][2], sacc[1][3]));
    float m2 = fmaxf(fmaxf(sacc[2][0], sacc[2][1]), fmaxf(sacc[2][2], sacc[2][3]));
    float m3 = fmaxf(fmaxf(sacc[3][0], sacc[3][1]), fmaxf(sacc[3][2], sacc[3][3]));
    float mx = fmaxf(fmaxf(m0, m1), fmaxf(m2, m3));
    mx = fmaxf(mx, __shfl_xor(mx, 16));
    mx = fmaxf(mx, __shfl_xor(mx, 32));

    if (!__all(mx - mrun <= 8.0f)) {           // T13 defer-max
      const float mnew = fmaxf(mrun, mx);
      const float fac = __expf(mrun - mnew);
      lrun *= fac;
      float facr[4];
#pragma unroll
      for (int r = 0; r < 4; ++r) facr[r] = __shfl(fac, hi * 4 + r);
#pragma unroll
      for (int ni = 0; ni < 4; ++ni)
#pragma unroll
        for (int r = 0; r < 4; ++r) oacc[ni][r] *= facr[r];
      mrun = mnew;
    }

    float sum = 0.f;
#pragma unroll
    for (int ni = 0; ni < 4; ++ni) {
#pragma unroll
      for (int t = 0; t < 2; ++t) {
        const float p0 = __expf(sacc[ni][2 * t]     - mrun);
        const float p1 = __expf(sacc[ni][2 * t + 1] - mrun);
        sum += p0 + p1;
        const unsigned int pk =
            (unsigned int)__builtin_bit_cast(unsigned short, (__bf16)p0) |
            ((unsigned int)__builtin_bit_cast(unsigned short, (__bf16)p1) << 16);
        *(unsigned int*)(pbase + ((32 * ni + 8 * hi + 4 * t) ^ swz)) = pk;
      }
    }
    sum += __shfl_xor(sum, 16);
    sum += __shfl_xor(sum, 32);
    lrun += sum;

#pragma unroll
    for (int kk = 0; kk < 2; ++kk) {
      bf16x8 ap = *(const bf16x8*)(pbase + ((kk * 64 + 16 * hi) ^ swz));
#pragma unroll
      for (int ni = 0; ni < 4; ++ni)
        oacc[ni] = MFMA16(ap, bv[ni][kk], oacc[ni]);
    }
  };

  for (int kt = 0; kt < nkt; ++kt) {
    const int cur = kt & 1;
    const bool more = (kt + 1 < nkt);
    const bool doL = (kt <= qtL);

    if (more) {
#pragma unroll
      for (int p = 0; p < 2; ++p) {
        const int seg = p * 4 + w;
        gload16(kmat + base + (long)((kt + 1) * 64 + seg * 8 + ks_row) * 3072 + ks_scol,
                (char*)lsK[cur ^ 1] + seg * 1024);
      }
      const long gv = base + (long)((kt + 1) * 64 + vs_key) * 3072 + vs_db;
      pv0 = *(const bf16x8*)&v[gv];
      pv1 = *(const bf16x8*)&v[gv + 8];
    }

    bf16x8 bk[4][2];
#pragma unroll
    for (int ni = 0; ni < 4; ++ni) {
      const int row = ni * 16 + lo;
#pragma unroll
      for (int kk = 0; kk < 2; ++kk)
        bk[ni][kk] = *(const bf16x8*)((char*)lsK[cur] + row * 128 +
                                      ((kk * 64 + 16 * hi) ^ ((row & 7) << 4)));
    }

    f32x4 sH[4], sL[4];
#pragma unroll
    for (int ni = 0; ni < 4; ++ni) { sH[ni] = fz; sL[ni] = fz; }
#pragma unroll
    for (int kk = 0; kk < 2; ++kk)
#pragma unroll
      for (int ni = 0; ni < 4; ++ni)
        sH[ni] = MFMA16(bk[ni][kk], aqH[kk], sH[ni]);
    if (doL) {
#pragma unroll
      for (int kk = 0; kk < 2; ++kk)
#pragma unroll
        for (int ni = 0; ni < 4; ++ni)
          sL[ni] = MFMA16(bk[ni][kk], aqL[kk], sL[ni]);
    }

    if (kt == qtH) {
      const int rg = qwH + lo;
#pragma unroll
      for (int ni = 0; ni < 4; ++ni)
#pragma unroll
        for (int r = 0; r < 4; ++r)
          if (kt * 64 + ni * 16 + hi * 4 + r > rg) sH[ni][r] = -1e9f;
    }
    if (doL && kt == qtL) {
      const int rg = qwL + lo;
#pragma unroll
      for (int ni = 0; ni < 4; ++ni)
#pragma unroll
        for (int r = 0; r < 4; ++r)
          if (kt * 64 + ni * 16 + hi * 4 + r > rg) sL[ni][r] = -1e9f;
    }

    bf16x8 bv[4][2];
#pragma unroll
    for (int ni = 0; ni < 4; ++ni) {
      const int d = ni * 16 + lo;
#pragma unroll
      for (int kk = 0; kk < 2; ++kk)
        bv[ni][kk] = *(const bf16x8*)((char*)lsV[cur] + d * 128 +
                                      ((kk * 64 + 16 * hi) ^ ((d & 7) << 4) ^ (((d >> 4) & 3) << 5)));
    }

    finish(sH, oaccH, mrunH, lrunH, bv);
    if (doL) finish(sL, oaccL, mrunL, lrunL, bv);

    if (more) {
      char* lv = (char*)lsV[cur ^ 1];
#pragma unroll
      for (int j = 0; j < 8; ++j) {
        const int d0 = vs_db + j, d1 = vs_db + 8 + j;
        *(__bf16*)(lv + d0 * 128 + ((vs_key * 2) ^ ((d0 & 7) << 4) ^ (((d0 >> 4) & 3) << 5))) = pv0[j];
        *(__bf16*)(lv + d1 * 128 + ((vs_key * 2) ^ ((d1 & 7) << 4) ^ (((d1 >> 4) & 3) << 5))) = pv1[j];
      }
    }
    __syncthreads();
  }

  float lprH[4], lprL[4];
#pragma unroll
  for (int r = 0; r < 4; ++r) {
    lprH[r] = __shfl(lrunH, hi * 4 + r);
    lprL[r] = __shfl(lrunL, hi * 4 + r);
  }
#pragma unroll
  for (int ni = 0; ni < 4; ++ni)
#pragma unroll
    for (int r = 0; r < 4; ++r) {
      const int rowH = qwH + hi * 4 + r;
      const int rowL = qwL + hi * 4 + r;
      o[obase + (long)rowH * 1024 + ni * 16 + lo] = (__bf16)(oaccH[ni][r] / lprH[r]);
      o[obase + (long)rowL * 1024 + ni * 16 + lo] = (__bf16)(oaccL[ni][r] / lprL[r]);
    }
}

// ---------------------------------------------------------------- launcher
extern "C" void kernel_launch(void* const* d_in, const int* in_sizes, int n_in,
                              void* d_out, int out_size, void* d_ws, size_t ws_size,
                              hipStream_t stream) {
  const float* x    = (const float*)d_in[0];
  const float* fr   = (const float*)d_in[1];
  const float* ln1g = (const float*)d_in[3];
  const float* ln1b = (const float*)d_in[4];
  const float* Wq   = (const float*)d_in[5];
  const float* bq   = (const float*)d_in[6];
  const float* Wk   = (const float*)d_in[7];
  const float* bk   = (const float*)d_in[8];
  const float* Wv   = (const float*)d_in[9];
  const float* bv   = (const float*)d_in[10];
  const float* Wo   = (const float*)d_in[11];
  const float* bo   = (const float*)d_in[12];
  const float* ln2g = (const float*)d_in[13];
  const float* ln2b = (const float*)d_in[14];
  const float* W1   = (const float*)d_in[15];
  const float* b1   = (const float*)d_in[16];
  const float* W2   = (const float*)d_in[17];
  const float* b2   = (const float*)d_in[18];
  float* out = (float*)d_out;

  char* ws = (char*)d_ws;
  const size_t SZ = 8388608;  // 8 MB
  __bf16* xn   = (__bf16*)(ws + 0);              // 8 MB
  __bf16* qkv  = (__bf16*)(ws + 1 * SZ);         // 24 MB (8..32)
  __bf16* attn = (__bf16*)(ws + 0);              // reuse xn
  float*  bqkv = (float*)(ws + 4 * SZ);          // 12 KB, dead before x2 written
  float*  x2   = (float*)(ws + 4 * SZ);          // 16 MB f32 (32..48)
  __bf16* hin  = (__bf16*)(ws + 6 * SZ);         // 8 MB (48..56)
  __bf16* hmid = (__bf16*)(ws + 0);              // 32 MB (0..32), qkv/attn dead
  char* wb = ws + 7 * SZ;                        // bf16 weights, 24 MB (56..80), contiguous
  __bf16* Wqkvb = (__bf16*)(wb + 0);             // 6 MB: Wq|Wk|Wv packed along N
  __bf16* Wob   = (__bf16*)(wb + 6 * 1048576);
  __bf16* W1b   = (__bf16*)(wb + 8 * 1048576);
  __bf16* W2b   = (__bf16*)(wb + 16 * 1048576);
  // split-K partials (FFN2): 3 x 8 MB bf16 at 48..72 — hin/Wqkvb/Wob/W1b are dead
  // by the time gemm256sk runs; cvt6 re-converts weights every launch.
  __bf16* part  = (__bf16*)(ws + 6 * SZ);

  const int M = 4096, D = 1024, FF = 4096;
  dim3 blk(256), blk5(512);

  cvt6_kernel<<<6144, blk, 0, stream>>>(Wq, Wk, Wv, Wo, W1, W2, Wqkvb);
  pack3_kernel<<<12, blk, 0, stream>>>(bq, bk, bv, bqkv);

  ln_kernel<<<4096, blk, 0, stream>>>(x, ln1g, ln1b, xn);
  gemm256<EPI_NONE, __bf16><<<dim3(3072 / 256, M / 256), blk5, 0, stream>>>(
      xn, Wqkvb, bqkv, qkv, M, 3072, D);
  rope_kernel<<<dim3(2048, 2), blk, 0, stream>>>(qkv, fr);
  attn_kernel<<<dim3(16, 16, 2), blk, 0, stream>>>(qkv, attn);
  gemm_bt<EPI_RES, float, 64><<<dim3(D / 64, M / 128), blk, 0, stream>>>(
      attn, Wob, bo, x, x2, M, D, D);
  ln_kernel<<<4096, blk, 0, stream>>>(x2, ln2g, ln2b, hin);
  gemm256<EPI_GELU, __bf16><<<dim3(FF / 256, M / 256), blk5, 0, stream>>>(
      hin, W1b, b1, hmid, M, FF, D);
  gemm256sk<<<dim3(D / 256, M / 256, 4), blk5, 0, stream>>>(
      hmid, W2b, part, out, M, D, FF, 16);
  comb_kernel<<<4096, blk, 0, stream>>>(part, b2, x2, out);
}